// Round 2
// baseline (4260.458 us; speedup 1.0000x reference)
//
#include <hip/hip_runtime.h>
#include <math.h>

#define BATCH 32
#define P_TOTAL 8732

// ---------------------------------------------------------------------------
// SSD DetectionOutput, fp32-faithful implementation.
// R2 change: conv_gemm accumulates in blocked f32->f64 (16-wide fp32 inner
// blocks summed into f64) to cut accumulation noise ~17x below the np/jax
// reference noise floor -- the R1 absmax=5.0 was a single label flip from a
// top-k/NMS decision whose margin our long serial fp32 chain crossed.
// ---------------------------------------------------------------------------

struct ScaleP {
  int C, logC, H, W, M, K, N, NL, npc, pbase;
  int ntiles, blkBase, wCum;
  int nhwcOff, wOff, bOff;
};
struct GemmArgs { ScaleP sp[6]; };
struct WPtrs { const float* lw[6]; const float* lb[6]; const float* cw[6]; const float* cb[6]; };

// ---------------- priors ----------------
__global__ void make_priors(float* __restrict__ priors) {
  int p = blockIdx.x * 256 + threadIdx.x;
  if (p >= P_TOTAL) return;
  const int pb1 = 5776, pb2 = 7942, pb3 = 8542, pb4 = 8692, pb5 = 8728;
  int base, fw, npc;
  double m, M, st;
  if (p < pb1)      { base = 0;   fw = 38; npc = 4; m = 30.;  M = 60.;  st = 8.;   }
  else if (p < pb2) { base = pb1; fw = 19; npc = 6; m = 60.;  M = 111.; st = 16.;  }
  else if (p < pb3) { base = pb2; fw = 10; npc = 6; m = 111.; M = 162.; st = 32.;  }
  else if (p < pb4) { base = pb3; fw = 5;  npc = 6; m = 162.; M = 213.; st = 64.;  }
  else if (p < pb5) { base = pb4; fw = 3;  npc = 4; m = 213.; M = 264.; st = 100.; }
  else              { base = pb5; fw = 1;  npc = 4; m = 264.; M = 315.; st = 300.; }
  int lp = p - base;
  int cell = lp / npc, j = lp - cell * npc;
  int y = cell / fw, x = cell - y * fw;
  double w_, h_;
  if (j == 0)      { w_ = m; h_ = m; }
  else if (j == 1) { double ss = sqrt(m * M); w_ = ss; h_ = ss; }
  else {
    int q = j - 2;
    double r = sqrt((q < 2) ? 2.0 : 3.0);
    if ((q & 1) == 0) { w_ = m * r; h_ = m / r; }
    else              { w_ = m / r; h_ = m * r; }
  }
  // numpy: wh cast to f32 first, THEN /300 in f32; cx in f64 then cast.
  float wf = (float)w_ / 300.0f;
  float hf = (float)h_ / 300.0f;
  float cx = (float)(((double)x + 0.5) * st / 300.0);
  float cy = (float)(((double)y + 0.5) * st / 300.0);
  float4 pr;
  pr.x = cx - wf * 0.5f; pr.y = cy - hf * 0.5f;
  pr.z = cx + wf * 0.5f; pr.w = cy + hf * 0.5f;
  ((float4*)priors)[p] = pr;
}

// ---------------- NCHW -> NHWC ----------------
__global__ void nchw_to_nhwc(const float* __restrict__ in, float* __restrict__ out,
                             int C, int HW) {
  __shared__ float tile[32][33];
  int b = blockIdx.z;
  int hw0 = blockIdx.x * 32;
  int c0 = blockIdx.y * 32;
  int tx = threadIdx.x;  // 0..31
  int ty = threadIdx.y;  // 0..7
  const float* ip = in + (size_t)b * C * HW;
  float* op = out + (size_t)b * C * HW;
#pragma unroll
  for (int r = 0; r < 4; ++r) {
    int c = c0 + ty + 8 * r;
    int hw = hw0 + tx;
    tile[ty + 8 * r][tx] = (c < C && hw < HW) ? ip[(size_t)c * HW + hw] : 0.f;
  }
  __syncthreads();
#pragma unroll
  for (int r = 0; r < 4; ++r) {
    int hw = hw0 + ty + 8 * r;
    int c = c0 + tx;
    if (c < C && hw < HW) op[(size_t)hw * C + c] = tile[tx][ty + 8 * r];
  }
}

// ---------------- weight repack ----------------
__global__ void prep_weights(WPtrs wp, GemmArgs ga, float* __restrict__ ws, int totalWN) {
  int e = blockIdx.x * 256 + threadIdx.x;
  if (e < totalWN) {
    int s = 0;
#pragma unroll
    for (int i = 1; i < 6; ++i) if (e >= ga.sp[i].wCum) s = i;
    const ScaleP sp = ga.sp[s];
    int le = e - sp.wCum;
    int n = le % sp.N;
    int k = le / sp.N;
    int tap = k >> sp.logC;
    int c = k & ((1 << sp.logC) - 1);
    float v;
    if (n < sp.NL) v = wp.lw[s][(n * sp.C + c) * 9 + tap];
    else           v = wp.cw[s][((n - sp.NL) * sp.C + c) * 9 + tap];
    ws[sp.wOff + k * sp.N + n] = v;
  } else {
    int e2 = e - totalWN;
    if (e2 >= 750) return;
    int s = 0, start = 0;
    for (int i = 0; i < 6; ++i) {
      int nn = ga.sp[i].N;
      if (e2 < start + nn) { s = i; break; }
      start += nn;
    }
    const ScaleP sp = ga.sp[s];
    int ln = e2 - start;
    ws[sp.bOff + ln] = (ln < sp.NL) ? wp.lb[s][ln] : wp.cb[s][ln - sp.NL];
  }
}

// ---------------- fused conv (implicit GEMM), all scales ----------------
__global__ __launch_bounds__(256) void conv_gemm(const float* __restrict__ ws, GemmArgs ga,
                                                 float* __restrict__ locbuf,
                                                 float* __restrict__ confbuf) {
  int bid = blockIdx.x;
  int s = 0;
#pragma unroll
  for (int i = 1; i < 6; ++i) if (bid >= ga.sp[i].blkBase) s = i;
  const ScaleP sp = ga.sp[s];
  const int lb = bid - sp.blkBase;
  const int mt = lb / sp.ntiles, ntb = lb - mt * sp.ntiles;
  const int m0 = mt * 128, n0 = ntb * 64;
  const int HW = sp.H * sp.W;
  const float* Amat = ws + sp.nhwcOff;
  const float* Wc = ws + sp.wOff;
  const float* bias = ws + sp.bOff;

  const int tid = threadIdx.x;
  const int tx = tid & 15, ty = tid >> 4;

  int ay[8], ax[8], arow[8];
  bool avalid[8];
#pragma unroll
  for (int r = 0; r < 8; ++r) {
    int mm = ty + 16 * r;
    int m = m0 + mm;
    bool v = (m < sp.M);
    int mc = v ? m : 0;
    int b = mc / HW, rem = mc - b * HW;
    int y = rem / sp.W, x = rem - y * sp.W;
    ay[r] = y; ax[r] = x; avalid[r] = v;
    arow[r] = (b * sp.H + y) * sp.W + x;
  }

  __shared__ float As[16 * 132];  // [k][m], stride 132 -> <=2-way bank aliasing
  __shared__ float Bs[16 * 64];   // [k][n]

  double acc[8][4];
#pragma unroll
  for (int i = 0; i < 8; ++i)
#pragma unroll
    for (int j = 0; j < 4; ++j) acc[i][j] = 0.;

  const int ksteps = sp.K >> 4;
  for (int kb = 0; kb < ksteps; ++kb) {
    const int k0 = kb << 4;
    const int tap = k0 >> sp.logC;
    const int c0 = k0 & ((1 << sp.logC) - 1);
    const int kyo = tap / 3 - 1;
    const int kxo = tap - (tap / 3) * 3 - 1;
    const int dl = (kyo * sp.W + kxo) * sp.C + c0 + tx;
#pragma unroll
    for (int r = 0; r < 8; ++r) {
      int iy = ay[r] + kyo, ix = ax[r] + kxo;
      bool v = avalid[r] && iy >= 0 && iy < sp.H && ix >= 0 && ix < sp.W;
      float val = v ? Amat[arow[r] * sp.C + dl] : 0.f;
      As[tx * 132 + ty + 16 * r] = val;
    }
#pragma unroll
    for (int r = 0; r < 4; ++r) {
      int kk = (tid >> 6) + 4 * r;
      int nn = tid & 63;
      int n = n0 + nn;
      Bs[kk * 64 + nn] = (n < sp.N) ? Wc[(k0 + kk) * sp.N + n] : 0.f;
    }
    __syncthreads();
    // fp32 inner block (full-rate FMA), promoted to f64 once per 16-wide block
    float facc[8][4];
#pragma unroll
    for (int i = 0; i < 8; ++i)
#pragma unroll
      for (int j = 0; j < 4; ++j) facc[i][j] = 0.f;
#pragma unroll
    for (int kk = 0; kk < 16; ++kk) {
      const float4 a0 = *(const float4*)&As[kk * 132 + ty * 8];
      const float4 a1 = *(const float4*)&As[kk * 132 + ty * 8 + 4];
      const float4 bv = *(const float4*)&Bs[kk * 64 + tx * 4];
      float av[8] = {a0.x, a0.y, a0.z, a0.w, a1.x, a1.y, a1.z, a1.w};
      float bb[4] = {bv.x, bv.y, bv.z, bv.w};
#pragma unroll
      for (int i = 0; i < 8; ++i)
#pragma unroll
        for (int j = 0; j < 4; ++j)
          facc[i][j] = fmaf(av[i], bb[j], facc[i][j]);
    }
    __syncthreads();
#pragma unroll
    for (int i = 0; i < 8; ++i)
#pragma unroll
      for (int j = 0; j < 4; ++j) acc[i][j] += (double)facc[i][j];
  }

#pragma unroll
  for (int i = 0; i < 8; ++i) {
    int m = m0 + ty * 8 + i;
    if (m >= sp.M) continue;
    int b = m / HW, rem = m - b * HW;
    int pidx0 = sp.pbase + rem * sp.npc;
#pragma unroll
    for (int j = 0; j < 4; ++j) {
      int n = n0 + tx * 4 + j;
      if (n >= sp.N) continue;
      float v = (float)acc[i][j] + bias[n];
      if (n < sp.NL) {
        locbuf[((long)b * P_TOTAL + pidx0 + (n >> 2)) * 4 + (n & 3)] = v;
      } else {
        int cn = n - sp.NL;
        int pr = cn / 21, cl = cn - pr * 21;
        confbuf[((long)b * P_TOTAL + pidx0 + pr) * 21 + cl] = v;
      }
    }
  }
}

// ---------------- softmax + box decode ----------------
__global__ __launch_bounds__(256) void decode_softmax(const float* __restrict__ locbuf,
                                                      const float* __restrict__ confbuf,
                                                      const float* __restrict__ priors,
                                                      float* __restrict__ boxes,
                                                      float* __restrict__ scores_t) {
  int t = blockIdx.x * 256 + threadIdx.x;
  if (t >= BATCH * P_TOTAL) return;
  int b = t / P_TOTAL, p = t - b * P_TOTAL;
  float4 pri = ((const float4*)priors)[p];
  float4 lo = ((const float4*)locbuf)[t];
  float pw = pri.z - pri.x, ph = pri.w - pri.y;
  float pcx = (pri.x + pri.z) * 0.5f, pcy = (pri.y + pri.w) * 0.5f;
  float cx = pcx + 0.1f * lo.x * pw;
  float cy = pcy + 0.1f * lo.y * ph;
  float w = pw * expf(0.2f * lo.z);
  float h = ph * expf(0.2f * lo.w);
  float4 bx;
  bx.x = cx - w * 0.5f; bx.y = cy - h * 0.5f;
  bx.z = cx + w * 0.5f; bx.w = cy + h * 0.5f;
  ((float4*)boxes)[t] = bx;

  const float* cp = confbuf + (long)t * 21;
  float l[21];
#pragma unroll
  for (int c = 0; c < 21; ++c) l[c] = cp[c];
  float mx = l[0];
#pragma unroll
  for (int c = 1; c < 21; ++c) mx = fmaxf(mx, l[c]);
  float e[21];
  float sum = 0.f;
#pragma unroll
  for (int c = 0; c < 21; ++c) { e[c] = expf(l[c] - mx); sum += e[c]; }
#pragma unroll
  for (int c = 1; c < 21; ++c)
    scores_t[((long)b * 20 + (c - 1)) * P_TOTAL + p] = e[c] / sum;
}

// ---------------- per-(image,class) top-200 + greedy NMS ----------------
__global__ __launch_bounds__(256) void topk_nms(const float* __restrict__ scores_t,
                                                const float* __restrict__ boxes,
                                                float* __restrict__ pc_scores,
                                                float* __restrict__ pc_boxes) {
  int bc = blockIdx.x;  // b*20 + c
  int b = bc / 20;
  int tid = threadIdx.x;
  const float* sp = scores_t + (long)bc * P_TOTAL;

  float vals[35];
#pragma unroll
  for (int u = 0; u < 35; ++u) {
    int idx = u * 256 + tid;
    float v = -1.f;  // -1 marks absent/removed; valid scores are >= 0
    if (idx < P_TOTAL) {
      float sc = sp[idx];
      v = (sc > 0.01f) ? sc : 0.f;  // CONF_THR, strict >
    }
    vals[u] = v;
  }

  __shared__ unsigned long long wred[4];
  __shared__ unsigned long long winner;
  __shared__ int sel_idx[200];
  __shared__ float sel_sc[200];
  __shared__ float bX1[200], bY1[200], bX2[200], bY2[200], bAr[200];

  for (int r = 0; r < 200; ++r) {
    float bv = vals[0]; int bu = 0;
#pragma unroll
    for (int u = 1; u < 35; ++u)
      if (vals[u] > bv) { bv = vals[u]; bu = u; }  // strict > keeps lowest idx
    int bidx = bu * 256 + tid;
    unsigned long long key = (bv < 0.f) ? 0ull
        : (((unsigned long long)__float_as_uint(bv) << 32) | (unsigned)(0x7FFFFFFF - bidx));
#pragma unroll
    for (int off = 32; off > 0; off >>= 1) {
      unsigned long long o = __shfl_down(key, off);
      if (o > key) key = o;
    }
    if ((tid & 63) == 0) wred[tid >> 6] = key;
    __syncthreads();
    if (tid == 0) {
      unsigned long long k0 = wred[0];
      for (int wv = 1; wv < 4; ++wv) if (wred[wv] > k0) k0 = wred[wv];
      winner = k0;
      sel_idx[r] = 0x7FFFFFFF - (int)(unsigned)(k0 & 0xFFFFFFFFu);
      sel_sc[r] = __uint_as_float((unsigned)(k0 >> 32));
    }
    __syncthreads();
    int wi = 0x7FFFFFFF - (int)(unsigned)(winner & 0xFFFFFFFFu);
    if ((wi & 255) == tid) {
      int u = wi >> 8;
#pragma unroll
      for (int uu = 0; uu < 35; ++uu) if (uu == u) vals[uu] = -1.f;
    }
    __syncthreads();
  }

  // gather selected boxes
  if (tid < 200) {
    int ii = sel_idx[tid];
    float4 bx = ((const float4*)boxes)[(long)b * P_TOTAL + ii];
    bX1[tid] = bx.x; bY1[tid] = bx.y; bX2[tid] = bx.z; bY2[tid] = bx.w;
    bAr[tid] = (bx.z - bx.x) * (bx.w - bx.y);
  }
  __syncthreads();

  // greedy NMS, wave 0 only (wave-synchronous, keep bits in registers)
  if (tid < 64) {
    float mx1[4], my1[4], mx2[4], my2[4], ma[4];
    unsigned km = 0;
#pragma unroll
    for (int s2 = 0; s2 < 4; ++s2) {
      int j = tid + 64 * s2;
      if (j < 200) {
        mx1[s2] = bX1[j]; my1[s2] = bY1[j]; mx2[s2] = bX2[j]; my2[s2] = bY2[j]; ma[s2] = bAr[j];
        if (sel_sc[j] > 0.f) km |= 1u << s2;
      } else {
        mx1[s2] = 0.f; my1[s2] = 0.f; mx2[s2] = 0.f; my2[s2] = 0.f; ma[s2] = 0.f;
      }
    }
    for (int i = 0; i < 200; ++i) {
      int owner = i & 63, slot = i >> 6;
      unsigned kmi = __shfl(km, owner);
      if ((kmi >> slot) & 1) {
        float ix1 = bX1[i], iy1 = bY1[i], ix2 = bX2[i], iy2 = bY2[i], ia = bAr[i];
#pragma unroll
        for (int s2 = 0; s2 < 4; ++s2) {
          int j = tid + 64 * s2;
          if (j < 200 && j > i) {
            float xx1 = fmaxf(ix1, mx1[s2]);
            float yy1 = fmaxf(iy1, my1[s2]);
            float xx2 = fminf(ix2, mx2[s2]);
            float yy2 = fminf(iy2, my2[s2]);
            float inter = fmaxf(xx2 - xx1, 0.f) * fmaxf(yy2 - yy1, 0.f);
            float uni = fmaxf(ia + ma[s2] - inter, 1e-9f);
            if (inter / uni > 0.45f) km &= ~(1u << s2);
          }
        }
      }
    }
#pragma unroll
    for (int s2 = 0; s2 < 4; ++s2) {
      int j = tid + 64 * s2;
      if (j < 200) {
        long o = (long)bc * 200 + j;
        pc_scores[o] = ((km >> s2) & 1) ? sel_sc[j] : 0.f;
        float4 ob; ob.x = mx1[s2]; ob.y = my1[s2]; ob.z = mx2[s2]; ob.w = my2[s2];
        ((float4*)pc_boxes)[o] = ob;
      }
    }
  }
}

// ---------------- final per-image top-200 + emit ----------------
__global__ __launch_bounds__(256) void final_topk(const float* __restrict__ pc_scores,
                                                  const float* __restrict__ pc_boxes,
                                                  float* __restrict__ out) {
  int b = blockIdx.x;
  int tid = threadIdx.x;
  const float* fs = pc_scores + (long)b * 4000;
  float vals[16];
#pragma unroll
  for (int u = 0; u < 16; ++u) {
    int idx = u * 256 + tid;
    vals[u] = (idx < 4000) ? fs[idx] : -1.f;
  }
  __shared__ unsigned long long wred[4];
  __shared__ unsigned long long winner;
  __shared__ int kidx[200];
  __shared__ float ksc[200];
  for (int r = 0; r < 200; ++r) {
    float bv = vals[0]; int bu = 0;
#pragma unroll
    for (int u = 1; u < 16; ++u)
      if (vals[u] > bv) { bv = vals[u]; bu = u; }
    int bidx = bu * 256 + tid;
    unsigned long long key = (bv < 0.f) ? 0ull
        : (((unsigned long long)__float_as_uint(bv) << 32) | (unsigned)(0x7FFFFFFF - bidx));
#pragma unroll
    for (int off = 32; off > 0; off >>= 1) {
      unsigned long long o = __shfl_down(key, off);
      if (o > key) key = o;
    }
    if ((tid & 63) == 0) wred[tid >> 6] = key;
    __syncthreads();
    if (tid == 0) {
      unsigned long long k0 = wred[0];
      for (int wv = 1; wv < 4; ++wv) if (wred[wv] > k0) k0 = wred[wv];
      winner = k0;
      kidx[r] = 0x7FFFFFFF - (int)(unsigned)(k0 & 0xFFFFFFFFu);
      ksc[r] = __uint_as_float((unsigned)(k0 >> 32));
    }
    __syncthreads();
    int wi = 0x7FFFFFFF - (int)(unsigned)(winner & 0xFFFFFFFFu);
    if ((wi & 255) == tid) {
      int u = wi >> 8;
#pragma unroll
      for (int uu = 0; uu < 16; ++uu) if (uu == u) vals[uu] = -1.f;
    }
    __syncthreads();
  }
  if (tid < 200) {
    int j = kidx[tid];
    float sc = ksc[tid];
    float4 bx = ((const float4*)pc_boxes)[(long)b * 4000 + j];
    float lab = (sc > 0.f) ? (float)(1 + j / 200) : -1.f;
    long o = ((long)b * 200 + tid) * 7;
    out[o + 0] = (float)b;
    out[o + 1] = lab;
    out[o + 2] = sc;
    out[o + 3] = bx.x; out[o + 4] = bx.y; out[o + 5] = bx.z; out[o + 6] = bx.w;
  }
}

// ---------------------------------------------------------------------------
extern "C" void kernel_launch(void* const* d_in, const int* in_sizes, int n_in,
                              void* d_out, int out_size, void* d_ws, size_t ws_size,
                              hipStream_t stream) {
  (void)in_sizes; (void)n_in; (void)out_size; (void)ws_size;
  static const int CH[6] = {512, 1024, 512, 256, 256, 256};
  static const int LOGC[6] = {9, 10, 9, 8, 8, 8};
  static const int FHW[6] = {38, 19, 10, 5, 3, 1};
  static const int NPC[6] = {4, 6, 6, 6, 4, 4};
  float* ws = (float*)d_ws;
  GemmArgs ga;
  WPtrs wp;
  size_t off = 0;
  auto align16 = [](size_t v) { return (v + 15) & ~(size_t)15; };
  int pb = 0;
  for (int s = 0; s < 6; ++s) {
    ScaleP& p = ga.sp[s];
    p.C = CH[s]; p.logC = LOGC[s]; p.H = FHW[s]; p.W = FHW[s];
    int hw = FHW[s] * FHW[s];
    p.M = BATCH * hw;
    p.K = CH[s] * 9;
    p.npc = NPC[s];
    p.NL = NPC[s] * 4;
    p.N = NPC[s] * 25;
    p.pbase = pb; pb += hw * NPC[s];
    p.nhwcOff = (int)off; off = align16(off + (size_t)BATCH * hw * CH[s]);
  }
  int wcum = 0;
  for (int s = 0; s < 6; ++s) {
    ga.sp[s].wOff = (int)off;
    ga.sp[s].wCum = wcum;
    wcum += ga.sp[s].K * ga.sp[s].N;
    off = align16(off + (size_t)ga.sp[s].K * ga.sp[s].N);
  }
  for (int s = 0; s < 6; ++s) { ga.sp[s].bOff = (int)off; off = align16(off + ga.sp[s].N); }
  int blkBase = 0;
  for (int s = 0; s < 6; ++s) {
    ScaleP& p = ga.sp[s];
    p.ntiles = (p.N + 63) / 64;
    int mtiles = (p.M + 127) / 128;
    p.blkBase = blkBase;
    blkBase += mtiles * p.ntiles;
  }
  int gemmBlocks = blkBase;
  size_t priorsOff = off; off = align16(off + (size_t)P_TOTAL * 4);
  size_t locOff    = off; off = align16(off + (size_t)BATCH * P_TOTAL * 4);
  size_t confOff   = off; off = align16(off + (size_t)BATCH * P_TOTAL * 21);
  size_t boxesOff  = off; off = align16(off + (size_t)BATCH * P_TOTAL * 4);
  size_t scTOff    = off; off = align16(off + (size_t)BATCH * 20 * P_TOTAL);
  size_t pcScOff   = off; off = align16(off + (size_t)BATCH * 20 * 200);
  size_t pcBxOff   = off; off = align16(off + (size_t)BATCH * 20 * 200 * 4);

  for (int s = 0; s < 6; ++s) {
    wp.lw[s] = (const float*)d_in[7 + 4 * s];
    wp.lb[s] = (const float*)d_in[8 + 4 * s];
    wp.cw[s] = (const float*)d_in[9 + 4 * s];
    wp.cb[s] = (const float*)d_in[10 + 4 * s];
  }

  make_priors<<<(P_TOTAL + 255) / 256, 256, 0, stream>>>(ws + priorsOff);

  for (int s = 0; s < 6; ++s) {
    int hw = FHW[s] * FHW[s];
    dim3 g((hw + 31) / 32, (CH[s] + 31) / 32, BATCH);
    nchw_to_nhwc<<<g, dim3(32, 8), 0, stream>>>((const float*)d_in[s], ws + ga.sp[s].nhwcOff,
                                                CH[s], hw);
  }

  prep_weights<<<(wcum + 750 + 255) / 256, 256, 0, stream>>>(wp, ga, ws, wcum);

  conv_gemm<<<gemmBlocks, 256, 0, stream>>>(ws, ga, ws + locOff, ws + confOff);

  decode_softmax<<<(BATCH * P_TOTAL + 255) / 256, 256, 0, stream>>>(
      ws + locOff, ws + confOff, ws + priorsOff, ws + boxesOff, ws + scTOff);

  topk_nms<<<BATCH * 20, 256, 0, stream>>>(ws + scTOff, ws + boxesOff,
                                           ws + pcScOff, ws + pcBxOff);

  final_topk<<<BATCH, 256, 0, stream>>>(ws + pcScOff, ws + pcBxOff, (float*)d_out);
}

// Round 3
// 1799.377 us; speedup vs baseline: 2.3677x; 2.3677x over previous
//
#include <hip/hip_runtime.h>
#include <math.h>

#define BATCH 32
#define P_TOTAL 8732

// ---------------------------------------------------------------------------
// SSD DetectionOutput. R3: conv heads moved to MFMA (bf16 3-way exact split,
// 6 products, two-level fp32 accumulation ~= R2 noise level).
// Pipeline: priors | nchw->nhwc f32 | zero(wpk+paux) | wpk_fill (packed MFMA
// frag layout, bf16x3) | bias_fill | conv_mfma<7> (s0,s4,s5 direct epilogue) |
// conv_mfma<10> (s1,s2,s3 split-K=2, atomic partials) | epi2 | decode_softmax
// (coalesced scores_t) | topk_nms | final_topk.
// ---------------------------------------------------------------------------

typedef __attribute__((ext_vector_type(8))) short bf16x8;
typedef __attribute__((ext_vector_type(4))) float f32x4;
typedef unsigned int uint;
typedef unsigned short ushort;

struct SQ {  // 16 ints = 64B
  int C, logC, H, W, HW, M, ksteps, NL, N, npc, pbase, blkBase;
  int aOffB, wpkOffB, pauxOffB, biasOffB;
};
struct WPtrs { const float* lw[6]; const float* lb[6]; const float* cw[6]; const float* cb[6]; };
struct Tables { SQ sq[6]; int fillBase[6]; int fillTotal; int biasBase[6]; int biasTotal; };

__device__ __forceinline__ ushort f2bf(float f) {
  uint u = __float_as_uint(f);
  return (ushort)((u + 0x7FFFu + ((u >> 16) & 1u)) >> 16);
}
__device__ __forceinline__ float bf2f(ushort b) { return __uint_as_float(((uint)b) << 16); }

// ---------------- priors (unchanged, verified R2) ----------------
__global__ void make_priors(float* __restrict__ priors) {
  int p = blockIdx.x * 256 + threadIdx.x;
  if (p >= P_TOTAL) return;
  const int pb1 = 5776, pb2 = 7942, pb3 = 8542, pb4 = 8692, pb5 = 8728;
  int base, fw, npc;
  double m, M, st;
  if (p < pb1)      { base = 0;   fw = 38; npc = 4; m = 30.;  M = 60.;  st = 8.;   }
  else if (p < pb2) { base = pb1; fw = 19; npc = 6; m = 60.;  M = 111.; st = 16.;  }
  else if (p < pb3) { base = pb2; fw = 10; npc = 6; m = 111.; M = 162.; st = 32.;  }
  else if (p < pb4) { base = pb3; fw = 5;  npc = 6; m = 162.; M = 213.; st = 64.;  }
  else if (p < pb5) { base = pb4; fw = 3;  npc = 4; m = 213.; M = 264.; st = 100.; }
  else              { base = pb5; fw = 1;  npc = 4; m = 264.; M = 315.; st = 300.; }
  int lp = p - base;
  int cell = lp / npc, j = lp - cell * npc;
  int y = cell / fw, x = cell - y * fw;
  double w_, h_;
  if (j == 0)      { w_ = m; h_ = m; }
  else if (j == 1) { double ss = sqrt(m * M); w_ = ss; h_ = ss; }
  else {
    int q = j - 2;
    double r = sqrt((q < 2) ? 2.0 : 3.0);
    if ((q & 1) == 0) { w_ = m * r; h_ = m / r; }
    else              { w_ = m / r; h_ = m * r; }
  }
  float wf = (float)w_ / 300.0f;
  float hf = (float)h_ / 300.0f;
  float cx = (float)(((double)x + 0.5) * st / 300.0);
  float cy = (float)(((double)y + 0.5) * st / 300.0);
  float4 pr;
  pr.x = cx - wf * 0.5f; pr.y = cy - hf * 0.5f;
  pr.z = cx + wf * 0.5f; pr.w = cy + hf * 0.5f;
  ((float4*)priors)[p] = pr;
}

// ---------------- NCHW -> NHWC f32 (unchanged) ----------------
__global__ void nchw_to_nhwc(const float* __restrict__ in, float* __restrict__ out,
                             int C, int HW) {
  __shared__ float tile[32][33];
  int b = blockIdx.z;
  int hw0 = blockIdx.x * 32;
  int c0 = blockIdx.y * 32;
  int tx = threadIdx.x;
  int ty = threadIdx.y;
  const float* ip = in + (size_t)b * C * HW;
  float* op = out + (size_t)b * C * HW;
#pragma unroll
  for (int r = 0; r < 4; ++r) {
    int c = c0 + ty + 8 * r;
    int hw = hw0 + tx;
    tile[ty + 8 * r][tx] = (c < C && hw < HW) ? ip[(size_t)c * HW + hw] : 0.f;
  }
  __syncthreads();
#pragma unroll
  for (int r = 0; r < 4; ++r) {
    int hw = hw0 + ty + 8 * r;
    int c = c0 + tx;
    if (c < C && hw < HW) op[(size_t)hw * C + c] = tile[tx][ty + 8 * r];
  }
}

// ---------------- zero workspace region ----------------
__global__ void zero_ws(uint4* __restrict__ p, long n) {
  uint4 z; z.x = z.y = z.z = z.w = 0u;
  for (long i = (long)blockIdx.x * 256 + threadIdx.x; i < n; i += (long)gridDim.x * 256)
    p[i] = z;
}

// ---------------- weight pack: bf16x3, per-lane MFMA fragment order ----------
// B-frag for mfma_f32_16x16x32_bf16: lane l holds B[k0 + 8*(l>>4)+i][16f + (l&15)]
__global__ void wpk_fill(WPtrs wp, Tables tb, char* __restrict__ wsb) {
  int e = blockIdx.x * 256 + threadIdx.x;
  if (e >= tb.fillTotal) return;
  int s = 0;
#pragma unroll
  for (int i = 1; i < 6; ++i) if (e >= tb.fillBase[i]) s = i;
  SQ q = tb.sq[s];
  int le = e - tb.fillBase[s];
  int C8 = q.C >> 3;
  int n = le / C8, co = (le - n * C8) * 8;
  const float* src = (n < q.NL) ? (wp.lw[s] + ((size_t)n * q.C + co) * 9)
                                : (wp.cw[s] + ((size_t)(n - q.NL) * q.C + co) * 9);
  float v[72];
#pragma unroll
  for (int i = 0; i < 72; ++i) v[i] = src[i];
  int f = n >> 4, ln = n & 15;
  int g = (co & 31) >> 3;
  int NF = (q.N + 15) >> 4;
  char* wbase = wsb + q.wpkOffB;
#pragma unroll
  for (int tap = 0; tap < 9; ++tap) {
    int kb = (tap * q.C + co) >> 5;
    ushort h0[8], h1[8], h2[8];
#pragma unroll
    for (int i = 0; i < 8; ++i) {
      float a = v[i * 9 + tap];
      ushort a0 = f2bf(a); float t = a - bf2f(a0);
      ushort a1 = f2bf(t); float t2 = t - bf2f(a1);
      ushort a2 = f2bf(t2);
      h0[i] = a0; h1[i] = a1; h2[i] = a2;
    }
    char* d = wbase + (size_t)kb * NF * 3072 + f * 3072 + (g * 16 + ln) * 16;
    *(uint4*)(d)        = *(uint4*)h0;
    *(uint4*)(d + 1024) = *(uint4*)h1;
    *(uint4*)(d + 2048) = *(uint4*)h2;
  }
}

// ---------------- bias pad fill ----------------
__global__ void bias_fill(WPtrs wp, Tables tb, char* __restrict__ wsb) {
  int e = blockIdx.x * 256 + threadIdx.x;
  if (e >= tb.biasTotal) return;
  int s = 0;
#pragma unroll
  for (int i = 1; i < 6; ++i) if (e >= tb.biasBase[i]) s = i;
  SQ q = tb.sq[s];
  int ln = e - tb.biasBase[s];
  float v = 0.f;
  if (ln < q.N) v = (ln < q.NL) ? wp.lb[s][ln] : wp.cb[s][ln - q.NL];
  ((float*)(wsb + q.biasOffB))[ln] = v;
}

// ---------------- split 8 floats -> 3 bf16 planes packed as uint4 ----------
__device__ __forceinline__ void split8(const float* vv, uint4& o0, uint4& o1, uint4& o2) {
  uint* a = (uint*)&o0; uint* b = (uint*)&o1; uint* c = (uint*)&o2;
#pragma unroll
  for (int i = 0; i < 4; ++i) {
    float x = vv[2 * i], y = vv[2 * i + 1];
    ushort x0 = f2bf(x); float xr = x - bf2f(x0);
    ushort x1 = f2bf(xr); ushort x2 = f2bf(xr - bf2f(x1));
    ushort y0 = f2bf(y); float yr = y - bf2f(y0);
    ushort y1 = f2bf(yr); ushort y2 = f2bf(yr - bf2f(y1));
    a[i] = (uint)x0 | ((uint)y0 << 16);
    b[i] = (uint)x1 | ((uint)y1 << 16);
    c[i] = (uint)x2 | ((uint)y2 << 16);
  }
}

// ---------------- MFMA conv, all-N-in-block, 128-row tiles ----------------
// A-frag: lane l holds A[m0 + (l&15)][k0 + 8*(l>>4)+i]  (As rows, 80B pitch)
// C/D:    col = lane&15, row = (lane>>4)*4 + reg        (m89/m91-verified)
template<int NF, bool PART>
__global__ __launch_bounds__(256, 2) void conv_mfma(const char* __restrict__ wsb,
                                                    SQ q0, SQ q1, SQ q2,
                                                    float* __restrict__ locbuf,
                                                    float* __restrict__ confbuf) {
  __shared__ char sm[30720 + NF * 3072];
  const int bid = blockIdx.x;
  SQ q = (bid >= q2.blkBase) ? q2 : ((bid >= q1.blkBase) ? q1 : q0);
  const int tid = threadIdx.x;
  const int C = q.C, W = q.W, H = q.H, HW = q.HW, M = q.M;
  int lb = bid - q.blkBase;
  int m0, kbeg, kend;
  if (PART) {
    m0 = (lb >> 1) * 128;
    int ks2 = q.ksteps >> 1;
    kbeg = (lb & 1) * ks2; kend = kbeg + ks2;
  } else {
    m0 = lb * 128; kbeg = 0; kend = q.ksteps;
  }
  const float* Amat = (const float*)(wsb + q.aOffB);
  const char* wpk = wsb + q.wpkOffB;

  // staging row assignment: thread handles rows r0 and r0+64, octet `oct`
  const int r0 = tid >> 2, oct = tid & 3;
  int ry[2], rx[2], rrow[2];  // rrow = b*H (pre-mult)
  bool rv[2];
#pragma unroll
  for (int h = 0; h < 2; ++h) {
    int m = m0 + r0 + 64 * h;
    bool v = m < M;
    int mc = v ? m : 0;
    int b = mc / HW, rem = mc - b * HW;
    ry[h] = rem / W; rx[h] = rem - ry[h] * W; rrow[h] = b * H; rv[h] = v;
  }

  f32x4 cb[2][NF], ct[2][NF];
#pragma unroll
  for (int rf = 0; rf < 2; ++rf)
#pragma unroll
    for (int f = 0; f < NF; ++f) { cb[rf][f] = 0.f; ct[rf][f] = 0.f; }

  const int lane = tid & 63, wv = tid >> 6;
  const int ksub = q.logC - 5, kmask = (1 << ksub) - 1;
  int abase[2];
#pragma unroll
  for (int rf = 0; rf < 2; ++rf)
    abase[rf] = (32 * wv + 16 * rf + (lane & 15)) * 80 + (lane >> 4) * 16;

  for (int kb = kbeg; kb < kend; ++kb) {
    int tap = kb >> ksub;
    int c0 = (kb & kmask) << 5;
    int t3 = tap * 21846 >> 16;  // tap/3 for tap<9
    int dy = t3 - 1, dx = tap - t3 * 3 - 1;
    __syncthreads();
    // stage A (f32 NHWC -> bf16x3 LDS planes)
#pragma unroll
    for (int h = 0; h < 2; ++h) {
      int iy = ry[h] + dy, ix = rx[h] + dx;
      bool ok = rv[h] && (unsigned)iy < (unsigned)H && (unsigned)ix < (unsigned)W;
      float4 f0, f1;
      f0.x = f0.y = f0.z = f0.w = 0.f; f1 = f0;
      if (ok) {
        const float* p = Amat + (size_t)((rrow[h] + iy) * W + ix) * C + c0 + oct * 8;
        f0 = ((const float4*)p)[0]; f1 = ((const float4*)p)[1];
      }
      float vv[8] = {f0.x, f0.y, f0.z, f0.w, f1.x, f1.y, f1.z, f1.w};
      uint4 o0, o1, o2;
      split8(vv, o0, o1, o2);
      int ab = (r0 + 64 * h) * 80 + oct * 16;
      *(uint4*)(sm + ab)         = o0;
      *(uint4*)(sm + 10240 + ab) = o1;
      *(uint4*)(sm + 20480 + ab) = o2;
    }
    // stage B (packed global -> LDS, linear copy)
    {
      const char* wsrc = wpk + (size_t)kb * (NF * 3072);
#pragma unroll
      for (int j = 0; j < (NF * 192 + 255) / 256; ++j) {
        int c = tid + j * 256;
        if (c < NF * 192) *(uint4*)(sm + 30720 + c * 16) = *(const uint4*)(wsrc + c * 16);
      }
    }
    __syncthreads();
    // compute
    bf16x8 a0[2], a1[2], a2[2];
#pragma unroll
    for (int rf = 0; rf < 2; ++rf) {
      a0[rf] = *(const bf16x8*)(sm + abase[rf]);
      a1[rf] = *(const bf16x8*)(sm + 10240 + abase[rf]);
      a2[rf] = *(const bf16x8*)(sm + 20480 + abase[rf]);
    }
#pragma unroll
    for (int f = 0; f < NF; ++f) {
      const char* bp = sm + 30720 + f * 3072 + lane * 16;
      bf16x8 b0 = *(const bf16x8*)(bp);
      bf16x8 b1 = *(const bf16x8*)(bp + 1024);
      bf16x8 b2 = *(const bf16x8*)(bp + 2048);
#pragma unroll
      for (int rf = 0; rf < 2; ++rf) {
        cb[rf][f] = __builtin_amdgcn_mfma_f32_16x16x32_bf16(a0[rf], b0, cb[rf][f], 0, 0, 0);
        cb[rf][f] = __builtin_amdgcn_mfma_f32_16x16x32_bf16(a1[rf], b0, cb[rf][f], 0, 0, 0);
        cb[rf][f] = __builtin_amdgcn_mfma_f32_16x16x32_bf16(a0[rf], b1, cb[rf][f], 0, 0, 0);
        cb[rf][f] = __builtin_amdgcn_mfma_f32_16x16x32_bf16(a1[rf], b1, cb[rf][f], 0, 0, 0);
        cb[rf][f] = __builtin_amdgcn_mfma_f32_16x16x32_bf16(a2[rf], b0, cb[rf][f], 0, 0, 0);
        cb[rf][f] = __builtin_amdgcn_mfma_f32_16x16x32_bf16(a0[rf], b2, cb[rf][f], 0, 0, 0);
      }
    }
    if (((kb - kbeg) & 15) == 15 || kb == kend - 1) {
#pragma unroll
      for (int rf = 0; rf < 2; ++rf)
#pragma unroll
        for (int f = 0; f < NF; ++f) { ct[rf][f] += cb[rf][f]; cb[rf][f] = 0.f; }
    }
  }

  // epilogue
  const float* bias = (const float*)(wsb + q.biasOffB);
#pragma unroll
  for (int rf = 0; rf < 2; ++rf) {
#pragma unroll
    for (int f = 0; f < NF; ++f) {
      int n = 16 * f + (lane & 15);
      if (n >= q.N) continue;
      int mrow = m0 + 32 * wv + 16 * rf + 4 * (lane >> 4);
      if (PART) {
        float* paux = (float*)(wsb + q.pauxOffB);
#pragma unroll
        for (int r = 0; r < 4; ++r) {
          int m = mrow + r;
          if (m < M) atomicAdd(&paux[(long)m * 160 + n], ct[rf][f][r]);
        }
      } else {
        float bv = bias[n];
#pragma unroll
        for (int r = 0; r < 4; ++r) {
          int m = mrow + r;
          if (m >= M) continue;
          float v = ct[rf][f][r] + bv;
          int b = m / HW, rem = m - b * HW;
          int pidx0 = q.pbase + rem * q.npc;
          if (n < q.NL) {
            locbuf[((long)b * P_TOTAL + pidx0 + (n >> 2)) * 4 + (n & 3)] = v;
          } else {
            int cn = n - q.NL;
            int pr = cn / 21, cl = cn - pr * 21;
            confbuf[((long)b * P_TOTAL + pidx0 + pr) * 21 + cl] = v;
          }
        }
      }
    }
  }
}

// ---------------- epilogue for split-K scales (1,2,3) ----------------
__global__ __launch_bounds__(256) void epi2(const char* __restrict__ wsb,
                                            SQ qa, SQ qb, SQ qc, int ta, int tb, int total,
                                            float* __restrict__ locbuf,
                                            float* __restrict__ confbuf) {
  int e = blockIdx.x * 256 + threadIdx.x;
  if (e >= total) return;
  SQ q; int le;
  if (e < ta) { q = qa; le = e; }
  else if (e < tb) { q = qb; le = e - ta; }
  else { q = qc; le = e - tb; }
  int m = le / q.N, n = le - m * q.N;
  float v = ((const float*)(wsb + q.pauxOffB))[(long)m * 160 + n]
          + ((const float*)(wsb + q.biasOffB))[n];
  int b = m / q.HW, rem = m - b * q.HW;
  int pidx0 = q.pbase + rem * q.npc;
  if (n < q.NL) {
    locbuf[((long)b * P_TOTAL + pidx0 + (n >> 2)) * 4 + (n & 3)] = v;
  } else {
    int cn = n - q.NL;
    int pr = cn / 21, cl = cn - pr * 21;
    confbuf[((long)b * P_TOTAL + pidx0 + pr) * 21 + cl] = v;
  }
}

// ---------------- softmax + box decode (coalesced scores_t writes) --------
__global__ __launch_bounds__(256) void decode_softmax(const float* __restrict__ locbuf,
                                                      const float* __restrict__ confbuf,
                                                      const float* __restrict__ priors,
                                                      float* __restrict__ boxes,
                                                      float* __restrict__ scores_t) {
  __shared__ float sc[20 * 256];
  int b = blockIdx.y;
  int p0 = blockIdx.x * 256;
  int tid = threadIdx.x;
  int p = p0 + tid;
  if (p < P_TOTAL) {
    long t = (long)b * P_TOTAL + p;
    float4 pri = ((const float4*)priors)[p];
    float4 lo = ((const float4*)locbuf)[t];
    float pw = pri.z - pri.x, ph = pri.w - pri.y;
    float pcx = (pri.x + pri.z) * 0.5f, pcy = (pri.y + pri.w) * 0.5f;
    float cx = pcx + 0.1f * lo.x * pw;
    float cy = pcy + 0.1f * lo.y * ph;
    float w = pw * expf(0.2f * lo.z);
    float h = ph * expf(0.2f * lo.w);
    float4 bx;
    bx.x = cx - w * 0.5f; bx.y = cy - h * 0.5f;
    bx.z = cx + w * 0.5f; bx.w = cy + h * 0.5f;
    ((float4*)boxes)[t] = bx;
    const float* cp = confbuf + t * 21;
    float l[21];
#pragma unroll
    for (int c = 0; c < 21; ++c) l[c] = cp[c];
    float mx = l[0];
#pragma unroll
    for (int c = 1; c < 21; ++c) mx = fmaxf(mx, l[c]);
    float e[21];
    float sum = 0.f;
#pragma unroll
    for (int c = 0; c < 21; ++c) { e[c] = expf(l[c] - mx); sum += e[c]; }
#pragma unroll
    for (int c = 1; c < 21; ++c) sc[(c - 1) * 256 + tid] = e[c] / sum;
  } else {
#pragma unroll
    for (int c = 0; c < 20; ++c) sc[c * 256 + tid] = 0.f;
  }
  __syncthreads();
  int np = min(256, P_TOTAL - p0);
  if (tid < np) {
    for (int c = 0; c < 20; ++c)
      scores_t[((long)b * 20 + c) * P_TOTAL + p0 + tid] = sc[c * 256 + tid];
  }
}

// ---------------- per-(image,class) top-200 + greedy NMS (R2, verified) ----
__global__ __launch_bounds__(256) void topk_nms(const float* __restrict__ scores_t,
                                                const float* __restrict__ boxes,
                                                float* __restrict__ pc_scores,
                                                float* __restrict__ pc_boxes) {
  int bc = blockIdx.x;
  int b = bc / 20;
  int tid = threadIdx.x;
  const float* sp = scores_t + (long)bc * P_TOTAL;

  float vals[35];
#pragma unroll
  for (int u = 0; u < 35; ++u) {
    int idx = u * 256 + tid;
    float v = -1.f;
    if (idx < P_TOTAL) {
      float s = sp[idx];
      v = (s > 0.01f) ? s : 0.f;
    }
    vals[u] = v;
  }

  __shared__ unsigned long long wred[4];
  __shared__ unsigned long long winner;
  __shared__ int sel_idx[200];
  __shared__ float sel_sc[200];
  __shared__ float bX1[200], bY1[200], bX2[200], bY2[200], bAr[200];

  for (int r = 0; r < 200; ++r) {
    float bv = vals[0]; int bu = 0;
#pragma unroll
    for (int u = 1; u < 35; ++u)
      if (vals[u] > bv) { bv = vals[u]; bu = u; }
    int bidx = bu * 256 + tid;
    unsigned long long key = (bv < 0.f) ? 0ull
        : (((unsigned long long)__float_as_uint(bv) << 32) | (unsigned)(0x7FFFFFFF - bidx));
#pragma unroll
    for (int off = 32; off > 0; off >>= 1) {
      unsigned long long o = __shfl_down(key, off);
      if (o > key) key = o;
    }
    if ((tid & 63) == 0) wred[tid >> 6] = key;
    __syncthreads();
    if (tid == 0) {
      unsigned long long k0 = wred[0];
      for (int w = 1; w < 4; ++w) if (wred[w] > k0) k0 = wred[w];
      winner = k0;
      sel_idx[r] = 0x7FFFFFFF - (int)(unsigned)(k0 & 0xFFFFFFFFu);
      sel_sc[r] = __uint_as_float((unsigned)(k0 >> 32));
    }
    __syncthreads();
    int wi = 0x7FFFFFFF - (int)(unsigned)(winner & 0xFFFFFFFFu);
    if ((wi & 255) == tid) {
      int u = wi >> 8;
#pragma unroll
      for (int uu = 0; uu < 35; ++uu) if (uu == u) vals[uu] = -1.f;
    }
    __syncthreads();
  }

  if (tid < 200) {
    int ii = sel_idx[tid];
    float4 bx = ((const float4*)boxes)[(long)b * P_TOTAL + ii];
    bX1[tid] = bx.x; bY1[tid] = bx.y; bX2[tid] = bx.z; bY2[tid] = bx.w;
    bAr[tid] = (bx.z - bx.x) * (bx.w - bx.y);
  }
  __syncthreads();

  if (tid < 64) {
    float mx1[4], my1[4], mx2[4], my2[4], ma[4];
    unsigned km = 0;
#pragma unroll
    for (int s2 = 0; s2 < 4; ++s2) {
      int j = tid + 64 * s2;
      if (j < 200) {
        mx1[s2] = bX1[j]; my1[s2] = bY1[j]; mx2[s2] = bX2[j]; my2[s2] = bY2[j]; ma[s2] = bAr[j];
        if (sel_sc[j] > 0.f) km |= 1u << s2;
      } else {
        mx1[s2] = 0.f; my1[s2] = 0.f; mx2[s2] = 0.f; my2[s2] = 0.f; ma[s2] = 0.f;
      }
    }
    for (int i = 0; i < 200; ++i) {
      int owner = i & 63, slot = i >> 6;
      unsigned kmi = __shfl(km, owner);
      if ((kmi >> slot) & 1) {
        float ix1 = bX1[i], iy1 = bY1[i], ix2 = bX2[i], iy2 = bY2[i], ia = bAr[i];
#pragma unroll
        for (int s2 = 0; s2 < 4; ++s2) {
          int j = tid + 64 * s2;
          if (j < 200 && j > i) {
            float xx1 = fmaxf(ix1, mx1[s2]);
            float yy1 = fmaxf(iy1, my1[s2]);
            float xx2 = fminf(ix2, mx2[s2]);
            float yy2 = fminf(iy2, my2[s2]);
            float inter = fmaxf(xx2 - xx1, 0.f) * fmaxf(yy2 - yy1, 0.f);
            float uni = fmaxf(ia + ma[s2] - inter, 1e-9f);
            if (inter / uni > 0.45f) km &= ~(1u << s2);
          }
        }
      }
    }
#pragma unroll
    for (int s2 = 0; s2 < 4; ++s2) {
      int j = tid + 64 * s2;
      if (j < 200) {
        long o = (long)bc * 200 + j;
        pc_scores[o] = ((km >> s2) & 1) ? sel_sc[j] : 0.f;
        float4 ob; ob.x = mx1[s2]; ob.y = my1[s2]; ob.z = mx2[s2]; ob.w = my2[s2];
        ((float4*)pc_boxes)[o] = ob;
      }
    }
  }
}

// ---------------- final per-image top-200 + emit (R2, verified) ----------
__global__ __launch_bounds__(256) void final_topk(const float* __restrict__ pc_scores,
                                                  const float* __restrict__ pc_boxes,
                                                  float* __restrict__ out) {
  int b = blockIdx.x;
  int tid = threadIdx.x;
  const float* fs = pc_scores + (long)b * 4000;
  float vals[16];
#pragma unroll
  for (int u = 0; u < 16; ++u) {
    int idx = u * 256 + tid;
    vals[u] = (idx < 4000) ? fs[idx] : -1.f;
  }
  __shared__ unsigned long long wred[4];
  __shared__ unsigned long long winner;
  __shared__ int kidx[200];
  __shared__ float ksc[200];
  for (int r = 0; r < 200; ++r) {
    float bv = vals[0]; int bu = 0;
#pragma unroll
    for (int u = 1; u < 16; ++u)
      if (vals[u] > bv) { bv = vals[u]; bu = u; }
    int bidx = bu * 256 + tid;
    unsigned long long key = (bv < 0.f) ? 0ull
        : (((unsigned long long)__float_as_uint(bv) << 32) | (unsigned)(0x7FFFFFFF - bidx));
#pragma unroll
    for (int off = 32; off > 0; off >>= 1) {
      unsigned long long o = __shfl_down(key, off);
      if (o > key) key = o;
    }
    if ((tid & 63) == 0) wred[tid >> 6] = key;
    __syncthreads();
    if (tid == 0) {
      unsigned long long k0 = wred[0];
      for (int w = 1; w < 4; ++w) if (wred[w] > k0) k0 = wred[w];
      winner = k0;
      kidx[r] = 0x7FFFFFFF - (int)(unsigned)(k0 & 0xFFFFFFFFu);
      ksc[r] = __uint_as_float((unsigned)(k0 >> 32));
    }
    __syncthreads();
    int wi = 0x7FFFFFFF - (int)(unsigned)(winner & 0xFFFFFFFFu);
    if ((wi & 255) == tid) {
      int u = wi >> 8;
#pragma unroll
      for (int uu = 0; uu < 16; ++uu) if (uu == u) vals[uu] = -1.f;
    }
    __syncthreads();
  }
  if (tid < 200) {
    int j = kidx[tid];
    float sc2 = ksc[tid];
    float4 bx = ((const float4*)pc_boxes)[(long)b * 4000 + j];
    float lab = (sc2 > 0.f) ? (float)(1 + j / 200) : -1.f;
    long o = ((long)b * 200 + tid) * 7;
    out[o + 0] = (float)b;
    out[o + 1] = lab;
    out[o + 2] = sc2;
    out[o + 3] = bx.x; out[o + 4] = bx.y; out[o + 5] = bx.z; out[o + 6] = bx.w;
  }
}

// ---------------------------------------------------------------------------
extern "C" void kernel_launch(void* const* d_in, const int* in_sizes, int n_in,
                              void* d_out, int out_size, void* d_ws, size_t ws_size,
                              hipStream_t stream) {
  (void)in_sizes; (void)n_in; (void)out_size; (void)ws_size;
  static const int CH[6]   = {512, 1024, 512, 256, 256, 256};
  static const int LOGC[6] = {9, 10, 9, 8, 8, 8};
  static const int FHW[6]  = {38, 19, 10, 5, 3, 1};
  static const int NPC[6]  = {4, 6, 6, 6, 4, 4};
  char* wsb = (char*)d_ws;
  Tables tb;
  WPtrs wp;
  auto al = [](size_t v) { return (v + 255) & ~(size_t)255; };
  size_t off = 0;
  int pb = 0;
  for (int s = 0; s < 6; ++s) {
    SQ& q = tb.sq[s];
    q.C = CH[s]; q.logC = LOGC[s]; q.H = FHW[s]; q.W = FHW[s];
    q.HW = FHW[s] * FHW[s];
    q.M = BATCH * q.HW;
    q.ksteps = CH[s] * 9 / 32;
    q.npc = NPC[s]; q.NL = NPC[s] * 4; q.N = NPC[s] * 25;
    q.pbase = pb; pb += q.HW * q.npc;
    q.aOffB = (int)off; off = al(off + (size_t)BATCH * q.HW * q.C * 4);
  }
  size_t zeroStart = off;
  for (int s = 0; s < 6; ++s) {
    int NF = (tb.sq[s].N + 15) >> 4;
    tb.sq[s].wpkOffB = (int)off;
    off = al(off + (size_t)tb.sq[s].ksteps * NF * 3072);
  }
  for (int s = 1; s <= 3; ++s) {
    tb.sq[s].pauxOffB = (int)off;
    off = al(off + (size_t)tb.sq[s].M * 160 * 4);
  }
  tb.sq[0].pauxOffB = tb.sq[4].pauxOffB = tb.sq[5].pauxOffB = 0;
  size_t zeroEnd = off;
  for (int s = 0; s < 6; ++s) {
    int NF = (tb.sq[s].N + 15) >> 4;
    tb.sq[s].biasOffB = (int)off;
    off = al(off + (size_t)NF * 16 * 4);
  }
  size_t priorsOffB = off; off = al(off + (size_t)P_TOTAL * 16);
  size_t locOffB    = off; off = al(off + (size_t)BATCH * P_TOTAL * 16);
  size_t confOffB   = off; off = al(off + (size_t)BATCH * P_TOTAL * 21 * 4);
  size_t boxesOffB  = off; off = al(off + (size_t)BATCH * P_TOTAL * 16);
  size_t scTOffB    = off; off = al(off + (size_t)BATCH * 20 * P_TOTAL * 4);
  size_t pcScOffB   = off; off = al(off + (size_t)BATCH * 20 * 200 * 4);
  size_t pcBxOffB   = off; off = al(off + (size_t)BATCH * 20 * 200 * 16);

  int fb = 0, bb = 0;
  for (int s = 0; s < 6; ++s) {
    tb.fillBase[s] = fb; fb += tb.sq[s].N * (tb.sq[s].C >> 3);
    tb.biasBase[s] = bb; bb += ((tb.sq[s].N + 15) >> 4) * 16;
  }
  tb.fillTotal = fb;   // 46400
  tb.biasTotal = bb;   // 816

  for (int s = 0; s < 6; ++s) {
    wp.lw[s] = (const float*)d_in[7 + 4 * s];
    wp.lb[s] = (const float*)d_in[8 + 4 * s];
    wp.cw[s] = (const float*)d_in[9 + 4 * s];
    wp.cb[s] = (const float*)d_in[10 + 4 * s];
  }

  float* priors   = (float*)(wsb + priorsOffB);
  float* locbuf   = (float*)(wsb + locOffB);
  float* confbuf  = (float*)(wsb + confOffB);
  float* boxes    = (float*)(wsb + boxesOffB);
  float* scores_t = (float*)(wsb + scTOffB);
  float* pcSc     = (float*)(wsb + pcScOffB);
  float* pcBx     = (float*)(wsb + pcBxOffB);

  make_priors<<<(P_TOTAL + 255) / 256, 256, 0, stream>>>(priors);

  for (int s = 0; s < 6; ++s) {
    int hw = FHW[s] * FHW[s];
    dim3 g((hw + 31) / 32, (CH[s] + 31) / 32, BATCH);
    nchw_to_nhwc<<<g, dim3(32, 8), 0, stream>>>((const float*)d_in[s],
                                                (float*)(wsb + tb.sq[s].aOffB), CH[s], hw);
  }

  long zn = (long)((zeroEnd - zeroStart) >> 4);
  zero_ws<<<4096, 256, 0, stream>>>((uint4*)(wsb + zeroStart), zn);

  wpk_fill<<<(tb.fillTotal + 255) / 256, 256, 0, stream>>>(wp, tb, wsb);
  bias_fill<<<(tb.biasTotal + 255) / 256, 256, 0, stream>>>(wp, tb, wsb);

  // launch 1: scales 0,4,5 (NF=7), direct epilogue
  {
    SQ q0 = tb.sq[0], q1 = tb.sq[4], q2 = tb.sq[5];
    q0.blkBase = 0;
    q1.blkBase = (q0.M + 127) / 128;                 // 361
    q2.blkBase = q1.blkBase + (q1.M + 127) / 128;    // 364
    int grid = q2.blkBase + (q2.M + 127) / 128;      // 365
    conv_mfma<7, false><<<grid, 256, 0, stream>>>(wsb, q0, q1, q2, locbuf, confbuf);
  }
  // launch 2: scales 1,2,3 (NF=10), split-K=2 atomic partials
  {
    SQ q0 = tb.sq[1], q1 = tb.sq[2], q2 = tb.sq[3];
    q0.blkBase = 0;
    q1.blkBase = 2 * ((q0.M + 127) / 128);           // 182
    q2.blkBase = q1.blkBase + 2 * ((q1.M + 127) / 128);  // 232
    int grid = q2.blkBase + 2 * ((q2.M + 127) / 128);    // 246
    conv_mfma<10, true><<<grid, 256, 0, stream>>>(wsb, q0, q1, q2, locbuf, confbuf);
    int ta = q0.M * q0.N;                  // 1732800
    int tbv = ta + q1.M * q1.N;            // 2212800
    int total = tbv + q2.M * q2.N;         // 2332800
    epi2<<<(total + 255) / 256, 256, 0, stream>>>(wsb, q0, q1, q2, ta, tbv, total,
                                                  locbuf, confbuf);
  }

  decode_softmax<<<dim3(35, BATCH), 256, 0, stream>>>(locbuf, confbuf, priors, boxes, scores_t);

  topk_nms<<<BATCH * 20, 256, 0, stream>>>(scores_t, boxes, pcSc, pcBx);

  final_topk<<<BATCH, 256, 0, stream>>>(pcSc, pcBx, (float*)d_out);
}